// Round 10
// baseline (929.432 us; speedup 1.0000x reference)
//
#include <hip/hip_runtime.h>
#include <hip/hip_bf16.h>
#include <stdint.h>

#define NTOK 131072
#define NEXP 8

typedef unsigned short ushortT;
typedef __attribute__((ext_vector_type(4))) float f32x4;
typedef __attribute__((ext_vector_type(8))) short s16x8;
typedef __attribute__((ext_vector_type(8))) __bf16 bf16x8;

__device__ __forceinline__ float bfu2f(unsigned short u){
  union { float f; uint32_t i; } c; c.i = ((uint32_t)u) << 16; return c.f;
}
__device__ __forceinline__ unsigned short f2bfu(float f){
  union { float f; uint32_t i; } c; c.f = f;
  uint32_t x = c.i;
  uint32_t r = (x + 0x7fffu + ((x >> 16) & 1u)) >> 16;  // RNE
  return (unsigned short)r;
}
// tanh-approx GELU (max abs err ~1e-3 vs erf form; threshold is 7e-2)
__device__ __forceinline__ float gelu_f(float x){
  float u = 0.7978845608028654f * (x + 0.044715f * x * x * x);
  float e = __expf(2.0f * u);
  float t = 1.0f - 2.0f / (e + 1.0f);
  return 0.5f * x * (1.0f + t);
}
__device__ __forceinline__ bf16x8 ldfrag(const void* p){
  s16x8 v = *(const s16x8*)p;
  return __builtin_bit_cast(bf16x8, v);
}

// async global->LDS, 16B per lane, wave-uniform LDS base + lane*16
#define GLOAD16(g_, l_) \
  __builtin_amdgcn_global_load_lds((const __attribute__((address_space(1))) uint32_t*)(g_), \
                                   (__attribute__((address_space(3))) uint32_t*)(l_), 16, 0, 0)

// ---- zero the routing cursors (kernel node instead of memset node) ----
__global__ __launch_bounds__(64) void zero_cursors_kernel(int* __restrict__ cursors){
  if (threadIdx.x < 16) cursors[threadIdx.x] = 0;
}

// ---- pack W1 [E][D][H] / W2 [E][H][O] fp32 -> bf16 MFMA B-fragment order ----
// frag id fi = (e*32 + nb)*16 + s   (nb = n/16, s = k/32)
// frag layout: lane l, elem j (8 per lane, 16B) = W[k0 + (l>>4)*8 + j][nb*16 + (l&15)]
__global__ __launch_bounds__(256) void prep_w_kernel(const float* __restrict__ W1,
                                                     const float* __restrict__ W2,
                                                     ushortT* __restrict__ W1f,
                                                     ushortT* __restrict__ W2f){
  int bid = blockIdx.x;   // 1024 = 2 mats * 8 e * 8 ktile * 8 ntile
  const float* src; ushortT* dst;
  if (bid < 512){ src = W1; dst = W1f; } else { src = W2; dst = W2f; bid -= 512; }
  int e  = bid >> 6;
  int kt = (bid >> 3) & 7;
  int nt = bid & 7;
  __shared__ ushortT tileT[64][68];   // [n_local][k_local]
  int t = threadIdx.x;
  #pragma unroll
  for (int i = 0; i < 16; i++){
    int idx = t + i*256;
    int r = idx >> 6, c = idx & 63;   // r = k_local, c = n_local
    float v = src[((size_t)(e*512 + kt*64 + r))*512 + nt*64 + c];
    tileT[c][r] = f2bfu(v);
  }
  __syncthreads();
  int sub = t >> 6, l = t & 63;
  #pragma unroll
  for (int fo = 0; fo < 2; fo++){
    int fr  = sub + fo*4;             // local frag 0..7
    int nbl = fr >> 1;                // 0..3
    int ks  = fr & 1;
    int nb  = nt*4 + nbl;
    size_t fi = ((size_t)(e*32 + nb))*16 + kt*2 + ks;
    ushortT tmp[8];
    #pragma unroll
    for (int j = 0; j < 8; j++)
      tmp[j] = tileT[nbl*16 + (l & 15)][ks*32 + (l >> 4)*8 + j];
    *(s16x8*)(dst + fi*512 + l*8) = *(s16x8*)tmp;
  }
}

// ---- gating: logits(fp32) -> top2 -> weights; also emit x as bf16 ----
__global__ __launch_bounds__(256) void gating_kernel(const float* __restrict__ x,
                                                     const float* __restrict__ Wg,
                                                     ushortT* __restrict__ xbf,
                                                     int* __restrict__ epair,
                                                     float* __restrict__ wt){
  int l = threadIdx.x & 63;
  int wv = threadIdx.x >> 6;
  f32x4 wgv[16];
  #pragma unroll
  for (int i = 0; i < 8; i++){
    const f32x4* p = (const f32x4*)(Wg + (size_t)(l*8 + i)*8);
    wgv[2*i] = p[0]; wgv[2*i+1] = p[1];
  }
  int tbase = (blockIdx.x * 4 + wv) * 16;
  for (int tt = 0; tt < 16; tt++){
    int t = tbase + tt;
    const f32x4* xr = (const f32x4*)(x + (size_t)t*512 + l*8);
    f32x4 xa = xr[0], xb = xr[1];
    float acc[8];
    #pragma unroll
    for (int e2 = 0; e2 < 8; e2++) acc[e2] = 0.f;
    #pragma unroll
    for (int i = 0; i < 4; i++){
      float xi = xa[i], xj = xb[i];
      #pragma unroll
      for (int e2 = 0; e2 < 4; e2++){
        acc[e2]   += xi * wgv[2*i][e2];
        acc[4+e2] += xi * wgv[2*i+1][e2];
        acc[e2]   += xj * wgv[2*(i+4)][e2];
        acc[4+e2] += xj * wgv[2*(i+4)+1][e2];
      }
    }
    #pragma unroll
    for (int off = 1; off < 64; off <<= 1){
      #pragma unroll
      for (int e2 = 0; e2 < 8; e2++) acc[e2] += __shfl_xor(acc[e2], off);
    }
    int e0 = 0; float v0 = acc[0];
    #pragma unroll
    for (int e2 = 1; e2 < 8; e2++) if (acc[e2] > v0){ v0 = acc[e2]; e0 = e2; }
    int e1 = -1; float v1 = -3.4e38f;
    #pragma unroll
    for (int e2 = 0; e2 < 8; e2++){ if (e2 != e0 && acc[e2] > v1){ v1 = acc[e2]; e1 = e2; } }
    float w0 = 1.f / (1.f + __expf(v1 - v0));
    if (l == 0){
      epair[t] = e0 | (e1 << 4);
      wt[t] = w0;
      wt[NTOK + t] = 1.f - w0;
    }
    s16x8 o;
    #pragma unroll
    for (int j = 0; j < 4; j++){ o[j] = (short)f2bfu(xa[j]); o[4+j] = (short)f2bfu(xb[j]); }
    *(s16x8*)(xbf + (size_t)t*512 + l*8) = o;
  }
}

// ---- routing scatter ----
__global__ __launch_bounds__(256) void scatter_kernel(const int* __restrict__ epair,
                                                      int* __restrict__ cursors,
                                                      int* __restrict__ lists){
  __shared__ int cntL[16]; __shared__ int baseL[16];
  int tid = threadIdx.x;
  if (tid < 16) cntL[tid] = 0;
  __syncthreads();
  int t = blockIdx.x * 256 + tid;
  int p = epair[t];
  int e0 = p & 15, e1 = (p >> 4) & 15;
  int lp0 = atomicAdd(&cntL[e0], 1);
  int lp1 = atomicAdd(&cntL[8 + e1], 1);
  __syncthreads();
  if (tid < 16) baseL[tid] = atomicAdd(&cursors[tid], cntL[tid]);
  __syncthreads();
  lists[(size_t)e0 * NTOK + baseL[e0] + lp0] = t;
  lists[(size_t)(8 + e1) * NTOK + baseL[8 + e1] + lp1] = t;
}

// ---- fused expert MLP: 64-token tile, 8 waves, wave-tile 64x64 ----
// W staged per K-step (BK=32, 32KB) via global_load_lds into a double-buffered
// LDS region; 2-phase schedule (stage s+1 || compute s, one barrier/step).
// X/h stays reg-staged + swizzled in its own 64KB buffer (R4-verified layout).
// LDS = 133KB -> 1 block/CU, 8 waves; (512,2) gives 256-reg budget.
template<int SLOT>
__global__ __launch_bounds__(512, 2) void expert_kernel(
    const ushortT* __restrict__ xbf, const ushortT* __restrict__ W1bf,
    const ushortT* __restrict__ W2bf, const float* __restrict__ gamma,
    const float* __restrict__ beta, const float* __restrict__ wt,
    const int* __restrict__ cursors, const int* __restrict__ lists,
    float* __restrict__ out)
{
  __shared__ ushortT hX[64 * 512];     // 64 KB X-then-h, rows 1024B, slot^(row&7) swizzle
  __shared__ ushortT Wb[2][16384];     // 2 x 32 KB W K-step stage buffers (linear)
  __shared__ int   toksL[64];
  __shared__ float wrowL[64];
  __shared__ float wsumL[8][64];
  __shared__ float wsqL[8][64];
  __shared__ float muL[64];
  __shared__ float rsL[64];

  int tid = threadIdx.x;
  int w = tid >> 6;
  int l = tid & 63;

  // XCD-chunked bijective swizzle: 2056 = 8*257
  int bid = (int)blockIdx.x;
  bid = (bid & 7) * 257 + (bid >> 3);

  // block -> (expert, tile) over 64-token tiles
  int e = -1, tile = 0, bacc = 0, cn = 0;
  #pragma unroll
  for (int i = 0; i < 8; i++){
    int c = cursors[SLOT*8 + i];
    int ntl = (c + 63) >> 6;
    if (e < 0 && bid < bacc + ntl){ e = i; tile = bid - bacc; cn = c; }
    bacc += ntl;
  }
  if (e < 0) return;
  int tb = tile * 64;
  const int* lbase = lists + (size_t)(SLOT*8 + e) * NTOK;

  const ushortT* w1base = W1bf + ((size_t)e*32)*16*512;
  const ushortT* w2base = W2bf + ((size_t)e*32)*16*512;

// stage the 4 W fragments owned by wave w for K-step s_ into buffer b_
#define STAGEW(wfb_, b_, s_) { \
    _Pragma("unroll") \
    for (int nf_ = 0; nf_ < 4; nf_++){ \
      const ushortT* gs_ = (wfb_) + ((size_t)(((w*4 + nf_)*16 + (s_))) << 9) + (l << 3); \
      GLOAD16(gs_, &Wb[b_][(w*4 + nf_) << 9]); \
    } }

  // stage W1 step 0 early (overlaps with toksL + X staging)
  STAGEW(w1base, 0, 0);

  if (tid < 64){
    int idx = tb + tid;
    int tok = (idx < cn) ? lbase[idx] : -1;
    toksL[tid] = tok;
    wrowL[tid] = (tok >= 0) ? wt[(size_t)SLOT*NTOK + tok] : 0.f;
  }

  // ---- stage full X tile (64 tok x 512 k) once, swizzled (reg-staged) ----
  {
    int r = tid >> 3, cs = tid & 7;
    int idx = tb + r; if (idx >= cn) idx = tb;      // clamp to a valid token
    int tokS = lbase[idx];
    const int4* xrow = (const int4*)(xbf + (size_t)tokS * 512);
    #pragma unroll
    for (int half = 0; half < 2; half++){
      int4 xv[4];
      #pragma unroll
      for (int i = 0; i < 4; i++) xv[i] = xrow[cs + (half*4 + i)*8];
      #pragma unroll
      for (int i = 0; i < 4; i++){
        int slot = cs + (half*4 + i)*8;
        int ss = slot ^ (r & 7);
        *(int4*)((char*)hX + r*1024 + ss*16) = xv[i];
      }
    }
  }
  __syncthreads();   // drains X ds_writes AND W1-step0 gload (vmcnt0 before barrier)

  // A-fragment LDS byte bases: row=(l&15)+m*16, slot = 4s + (l>>4)
  // byte = (l&15)*1024 + m*16384 + (s>>1)*128 + (((s&1)*4+(l>>4)) ^ (l&7))<<4
  const int aB0 = (l & 15)*1024 + ((((l >> 4)    ) ^ (l & 7)) << 4);
  const int aB1 = (l & 15)*1024 + (((4 + (l >> 4)) ^ (l & 7)) << 4);
  const char* Xp = (const char*)hX;

  f32x4 acc[4][4];

#define MFMAS() { \
    _Pragma("unroll") \
    for (int nf = 0; nf < 4; nf++) \
      _Pragma("unroll") \
      for (int m = 0; m < 4; m++) \
        acc[m][nf] = __builtin_amdgcn_mfma_f32_16x16x32_bf16(A[m], B[nf], acc[m][nf], 0, 0, 0); }

  // ================= GEMM1: acc = X @ W1 (2-phase, 1 barrier/step) ==========
  #pragma unroll
  for (int m = 0; m < 4; m++)
    #pragma unroll
    for (int nf = 0; nf < 4; nf++) acc[m][nf] = (f32x4){0.f,0.f,0.f,0.f};

  for (int s = 0; s < 16; s++){
    int cur = s & 1;
    if (s < 15) STAGEW(w1base, cur ^ 1, s + 1)
    else        STAGEW(w2base, 0, 0)            // pre-stage W2 step0 into buf0 (free since s=14)
    bf16x8 B[4], A[4];
    #pragma unroll
    for (int nf = 0; nf < 4; nf++)
      B[nf] = ldfrag(&Wb[cur][((w*4 + nf) << 9) + (l << 3)]);
    {
      const int ab = (s & 1) ? aB1 : aB0;
      #pragma unroll
      for (int m = 0; m < 4; m++)
        A[m] = ldfrag(Xp + ab + m*16384 + (s >> 1)*128);
    }
    MFMAS();
    __syncthreads();   // drains this step's stage; next buffer ready
  }

  // ---- LN partial sums from fp32 acc (regs) ----
  #pragma unroll
  for (int m = 0; m < 4; m++){
    #pragma unroll
    for (int j = 0; j < 4; j++){
      float s = acc[m][0][j] + acc[m][1][j] + acc[m][2][j] + acc[m][3][j];
      float q = acc[m][0][j]*acc[m][0][j] + acc[m][1][j]*acc[m][1][j]
              + acc[m][2][j]*acc[m][2][j] + acc[m][3][j]*acc[m][3][j];
      s += __shfl_xor(s, 1); q += __shfl_xor(q, 1);
      s += __shfl_xor(s, 2); q += __shfl_xor(q, 2);
      s += __shfl_xor(s, 4); q += __shfl_xor(q, 4);
      s += __shfl_xor(s, 8); q += __shfl_xor(q, 8);
      if ((l & 15) == 0){
        int row = m*16 + (l >> 4)*4 + j;
        wsumL[w][row] = s;
        wsqL[w][row]  = q;
      }
    }
  }
  __syncthreads();   // X reads done + partials written

  if (tid < 64){
    float s = 0.f, q = 0.f;
    #pragma unroll
    for (int i = 0; i < 8; i++){ s += wsumL[i][tid]; q += wsqL[i][tid]; }
    float mu = s * (1.f/512.f);
    float var = q * (1.f/512.f) - mu*mu;
    muL[tid] = mu;
    rsL[tid] = rsqrtf(var + 1e-5f);
  }
  __syncthreads();

  // ---- LN + GELU in registers, write h (bf16) into hX (overwrite X) ----
  {
    float g[4], b[4];
    #pragma unroll
    for (int nf = 0; nf < 4; nf++){
      int col = w*64 + nf*16 + (l & 15);
      g[nf] = gamma[e*512 + col];
      b[nf] = beta [e*512 + col];
    }
    #pragma unroll
    for (int m = 0; m < 4; m++){
      #pragma unroll
      for (int j = 0; j < 4; j++){
        int row = m*16 + (l >> 4)*4 + j;
        float mu = muL[row], rs = rsL[row];
        #pragma unroll
        for (int nf = 0; nf < 4; nf++){
          int col = w*64 + nf*16 + (l & 15);
          float v = (acc[m][nf][j] - mu) * rs * g[nf] + b[nf];
          v = gelu_f(v);
          int ss = (col >> 3) ^ (row & 7);
          *(ushortT*)((char*)hX + row*1024 + ss*16 + (col & 7)*2) = f2bfu(v);
        }
      }
    }
  }
  __syncthreads();

  // ================= GEMM2: out-tile = h @ W2 (2-phase) =================
  #pragma unroll
  for (int m = 0; m < 4; m++)
    #pragma unroll
    for (int nf = 0; nf < 4; nf++) acc[m][nf] = (f32x4){0.f,0.f,0.f,0.f};

  for (int s = 0; s < 16; s++){
    int cur = s & 1;
    if (s < 15) STAGEW(w2base, cur ^ 1, s + 1)
    bf16x8 B[4], A[4];
    #pragma unroll
    for (int nf = 0; nf < 4; nf++)
      B[nf] = ldfrag(&Wb[cur][((w*4 + nf) << 9) + (l << 3)]);
    {
      const int ab = (s & 1) ? aB1 : aB0;
      #pragma unroll
      for (int m = 0; m < 4; m++)
        A[m] = ldfrag(Xp + ab + m*16384 + (s >> 1)*128);
    }
    MFMAS();
    __syncthreads();
  }

  // ---- weighted store ----
  #pragma unroll
  for (int m = 0; m < 4; m++){
    #pragma unroll
    for (int j = 0; j < 4; j++){
      int row = m*16 + (l >> 4)*4 + j;
      int tok = toksL[row];
      if (tok >= 0){
        float wr = wrowL[row];
        #pragma unroll
        for (int nf = 0; nf < 4; nf++){
          int col = w*64 + nf*16 + (l & 15);
          float val = acc[m][nf][j] * wr;
          float* p = out + (size_t)tok*512 + col;
          if (SLOT == 0) *p = val; else *p += val;
        }
      }
    }
  }
#undef STAGEW
#undef MFMAS
}

extern "C" void kernel_launch(void* const* d_in, const int* in_sizes, int n_in,
                              void* d_out, int out_size, void* d_ws, size_t ws_size,
                              hipStream_t stream){
  const float* x     = (const float*)d_in[0];
  const float* Wg    = (const float*)d_in[1];
  const float* W1    = (const float*)d_in[2];
  const float* gamma = (const float*)d_in[3];
  const float* beta  = (const float*)d_in[4];
  const float* W2    = (const float*)d_in[5];
  float* out = (float*)d_out;

  char* ws = (char*)d_ws;
  size_t off = 0;
  ushortT* xbf   = (ushortT*)(ws + off); off += (size_t)NTOK*512*2;      // 128 MB
  ushortT* W1bf  = (ushortT*)(ws + off); off += (size_t)8*512*512*2;     // 4 MB
  ushortT* W2bf  = (ushortT*)(ws + off); off += (size_t)8*512*512*2;     // 4 MB
  int*     lists = (int*)(ws + off);     off += (size_t)16*NTOK*4;       // 8 MB
  float*   wtp   = (float*)(ws + off);   off += (size_t)2*NTOK*4;        // 1 MB
  int*     epair = (int*)(ws + off);     off += (size_t)NTOK*4;          // 0.5 MB
  int*     cursors = (int*)(ws + off);   off += 256;

  zero_cursors_kernel<<<1, 64, 0, stream>>>(cursors);
  prep_w_kernel<<<1024, 256, 0, stream>>>(W1, W2, W1bf, W2bf);
  gating_kernel<<<NTOK/64, 256, 0, stream>>>(x, Wg, xbf, epair, wtp);
  scatter_kernel<<<NTOK/256, 256, 0, stream>>>(epair, cursors, lists);
  expert_kernel<0><<<2056, 512, 0, stream>>>(xbf, W1bf, W2bf, gamma, beta, wtp, cursors, lists, out);
  expert_kernel<1><<<2056, 512, 0, stream>>>(xbf, W1bf, W2bf, gamma, beta, wtp, cursors, lists, out);
}

// Round 12
// 721.606 us; speedup vs baseline: 1.2880x; 1.2880x over previous
//
#include <hip/hip_runtime.h>
#include <hip/hip_bf16.h>
#include <stdint.h>

#define NTOK 131072
#define NEXP 8

typedef unsigned short ushortT;
typedef __attribute__((ext_vector_type(4))) float f32x4;
typedef __attribute__((ext_vector_type(8))) short s16x8;
typedef __attribute__((ext_vector_type(8))) __bf16 bf16x8;

__device__ __forceinline__ float bfu2f(unsigned short u){
  union { float f; uint32_t i; } c; c.i = ((uint32_t)u) << 16; return c.f;
}
__device__ __forceinline__ unsigned short f2bfu(float f){
  union { float f; uint32_t i; } c; c.f = f;
  uint32_t x = c.i;
  uint32_t r = (x + 0x7fffu + ((x >> 16) & 1u)) >> 16;  // RNE
  return (unsigned short)r;
}
// tanh-approx GELU (max abs err ~1e-3 vs erf form; threshold is 7e-2)
__device__ __forceinline__ float gelu_f(float x){
  float u = 0.7978845608028654f * (x + 0.044715f * x * x * x);
  float e = __expf(2.0f * u);
  float t = 1.0f - 2.0f / (e + 1.0f);
  return 0.5f * x * (1.0f + t);
}
__device__ __forceinline__ bf16x8 ldfrag(const void* p){
  s16x8 v = *(const s16x8*)p;
  return __builtin_bit_cast(bf16x8, v);
}

// ---- zero the routing cursors (kernel node instead of memset node) ----
__global__ __launch_bounds__(64) void zero_cursors_kernel(int* __restrict__ cursors){
  if (threadIdx.x < 16) cursors[threadIdx.x] = 0;
}

// ---- pack W1 [E][D][H] / W2 [E][H][O] fp32 -> bf16 MFMA B-fragment order ----
// frag id fi = (e*32 + nb)*16 + s   (nb = n/16, s = k/32)
// frag layout: lane l, elem j (8 per lane, 16B) = W[k0 + (l>>4)*8 + j][nb*16 + (l&15)]
__global__ __launch_bounds__(256) void prep_w_kernel(const float* __restrict__ W1,
                                                     const float* __restrict__ W2,
                                                     ushortT* __restrict__ W1f,
                                                     ushortT* __restrict__ W2f){
  int bid = blockIdx.x;   // 1024 = 2 mats * 8 e * 8 ktile * 8 ntile
  const float* src; ushortT* dst;
  if (bid < 512){ src = W1; dst = W1f; } else { src = W2; dst = W2f; bid -= 512; }
  int e  = bid >> 6;
  int kt = (bid >> 3) & 7;
  int nt = bid & 7;
  __shared__ ushortT tileT[64][68];   // [n_local][k_local]
  int t = threadIdx.x;
  #pragma unroll
  for (int i = 0; i < 16; i++){
    int idx = t + i*256;
    int r = idx >> 6, c = idx & 63;   // r = k_local, c = n_local
    float v = src[((size_t)(e*512 + kt*64 + r))*512 + nt*64 + c];
    tileT[c][r] = f2bfu(v);
  }
  __syncthreads();
  int sub = t >> 6, l = t & 63;
  #pragma unroll
  for (int fo = 0; fo < 2; fo++){
    int fr  = sub + fo*4;             // local frag 0..7
    int nbl = fr >> 1;                // 0..3
    int ks  = fr & 1;
    int nb  = nt*4 + nbl;
    size_t fi = ((size_t)(e*32 + nb))*16 + kt*2 + ks;
    ushortT tmp[8];
    #pragma unroll
    for (int j = 0; j < 8; j++)
      tmp[j] = tileT[nbl*16 + (l & 15)][ks*32 + (l >> 4)*8 + j];
    *(s16x8*)(dst + fi*512 + l*8) = *(s16x8*)tmp;
  }
}

// ---- gating: logits(fp32) -> top2 -> weights; also emit x as bf16 ----
__global__ __launch_bounds__(256) void gating_kernel(const float* __restrict__ x,
                                                     const float* __restrict__ Wg,
                                                     ushortT* __restrict__ xbf,
                                                     int* __restrict__ epair,
                                                     float* __restrict__ wt){
  int l = threadIdx.x & 63;
  int wv = threadIdx.x >> 6;
  f32x4 wgv[16];
  #pragma unroll
  for (int i = 0; i < 8; i++){
    const f32x4* p = (const f32x4*)(Wg + (size_t)(l*8 + i)*8);
    wgv[2*i] = p[0]; wgv[2*i+1] = p[1];
  }
  int tbase = (blockIdx.x * 4 + wv) * 16;
  for (int tt = 0; tt < 16; tt++){
    int t = tbase + tt;
    const f32x4* xr = (const f32x4*)(x + (size_t)t*512 + l*8);
    f32x4 xa = xr[0], xb = xr[1];
    float acc[8];
    #pragma unroll
    for (int e2 = 0; e2 < 8; e2++) acc[e2] = 0.f;
    #pragma unroll
    for (int i = 0; i < 4; i++){
      float xi = xa[i], xj = xb[i];
      #pragma unroll
      for (int e2 = 0; e2 < 4; e2++){
        acc[e2]   += xi * wgv[2*i][e2];
        acc[4+e2] += xi * wgv[2*i+1][e2];
        acc[e2]   += xj * wgv[2*(i+4)][e2];
        acc[4+e2] += xj * wgv[2*(i+4)+1][e2];
      }
    }
    #pragma unroll
    for (int off = 1; off < 64; off <<= 1){
      #pragma unroll
      for (int e2 = 0; e2 < 8; e2++) acc[e2] += __shfl_xor(acc[e2], off);
    }
    int e0 = 0; float v0 = acc[0];
    #pragma unroll
    for (int e2 = 1; e2 < 8; e2++) if (acc[e2] > v0){ v0 = acc[e2]; e0 = e2; }
    int e1 = -1; float v1 = -3.4e38f;
    #pragma unroll
    for (int e2 = 0; e2 < 8; e2++){ if (e2 != e0 && acc[e2] > v1){ v1 = acc[e2]; e1 = e2; } }
    float w0 = 1.f / (1.f + __expf(v1 - v0));
    if (l == 0){
      epair[t] = e0 | (e1 << 4);
      wt[t] = w0;
      wt[NTOK + t] = 1.f - w0;
    }
    s16x8 o;
    #pragma unroll
    for (int j = 0; j < 4; j++){ o[j] = (short)f2bfu(xa[j]); o[4+j] = (short)f2bfu(xb[j]); }
    *(s16x8*)(xbf + (size_t)t*512 + l*8) = o;
  }
}

// ---- routing scatter ----
__global__ __launch_bounds__(256) void scatter_kernel(const int* __restrict__ epair,
                                                      int* __restrict__ cursors,
                                                      int* __restrict__ lists){
  __shared__ int cntL[16]; __shared__ int baseL[16];
  int tid = threadIdx.x;
  if (tid < 16) cntL[tid] = 0;
  __syncthreads();
  int t = blockIdx.x * 256 + tid;
  int p = epair[t];
  int e0 = p & 15, e1 = (p >> 4) & 15;
  int lp0 = atomicAdd(&cntL[e0], 1);
  int lp1 = atomicAdd(&cntL[8 + e1], 1);
  __syncthreads();
  if (tid < 16) baseL[tid] = atomicAdd(&cursors[tid], cntL[tid]);
  __syncthreads();
  lists[(size_t)e0 * NTOK + baseL[e0] + lp0] = t;
  lists[(size_t)(8 + e1) * NTOK + baseL[8 + e1] + lp1] = t;
}

// ---- fused expert MLP: 64-token tile, 8 waves, wave-tile 64x64 (R4 geometry),
//      B-loads via inline-asm global_load_dwordx4 (64-bit VGPR address, "off"
//      form — the "s" saddr form fails: wave-uniform-but-thread-dependent bases
//      are divergent to LLVM) + counted s_waitcnt vmcnt(N): double-buffered
//      B0/B1, 8 loads in flight, vmcnt(4) steady state, vmcnt(0) last step.
//      The waitcnt asm ties the B registers ("+v") so MFMAs depend on the WAIT.
template<int SLOT>
__global__ __launch_bounds__(512, 4) void expert_kernel(
    const ushortT* __restrict__ xbf, const ushortT* __restrict__ W1bf,
    const ushortT* __restrict__ W2bf, const float* __restrict__ gamma,
    const float* __restrict__ beta, const float* __restrict__ wt,
    const int* __restrict__ cursors, const int* __restrict__ lists,
    float* __restrict__ out)
{
  __shared__ ushortT hX[64 * 512];     // 64 KB X-then-h, rows 1024B, slot^(row&7) swizzle
  __shared__ int   toksL[64];
  __shared__ float wrowL[64];
  __shared__ float wsumL[8][64];
  __shared__ float wsqL[8][64];
  __shared__ float muL[64];
  __shared__ float rsL[64];

  int tid = threadIdx.x;
  int w = tid >> 6;
  int l = tid & 63;

  // XCD-chunked bijective swizzle: 2056 = 8*257
  int bid = (int)blockIdx.x;
  bid = (bid & 7) * 257 + (bid >> 3);

  // block -> (expert, tile)
  int e = -1, tile = 0, bacc = 0, cn = 0;
  #pragma unroll
  for (int i = 0; i < 8; i++){
    int c = cursors[SLOT*8 + i];
    int ntl = (c + 63) >> 6;
    if (e < 0 && bid < bacc + ntl){ e = i; tile = bid - bacc; cn = c; }
    bacc += ntl;
  }
  if (e < 0) return;
  int tb = tile * 64;
  const int* lbase = lists + (size_t)(SLOT*8 + e) * NTOK;

  if (tid < 64){
    int idx = tb + tid;
    int tok = (idx < cn) ? lbase[idx] : -1;
    toksL[tid] = tok;
    wrowL[tid] = (tok >= 0) ? wt[(size_t)SLOT*NTOK + tok] : 0.f;
  }

  // ---- stage full X tile (64 tok x 512 k) once, swizzled ----
  {
    int r = tid >> 3, cs = tid & 7;
    int idx = tb + r; if (idx >= cn) idx = tb;      // clamp to a valid token
    int tokS = lbase[idx];
    const int4* xrow = (const int4*)(xbf + (size_t)tokS * 512);
    #pragma unroll
    for (int half = 0; half < 2; half++){
      int4 xv[4];
      #pragma unroll
      for (int i = 0; i < 4; i++) xv[i] = xrow[cs + (half*4 + i)*8];
      #pragma unroll
      for (int i = 0; i < 4; i++){
        int slot = cs + (half*4 + i)*8;
        int ss = slot ^ (r & 7);
        *(int4*)((char*)hX + r*1024 + ss*16) = xv[i];
      }
    }
  }
  __syncthreads();

  // A-fragment LDS byte bases: row=(l&15)+m*16, slot = 4s + (l>>4)
  const int aB0 = (l & 15)*1024 + ((((l >> 4)    ) ^ (l & 7)) << 4);
  const int aB1 = (l & 15)*1024 + (((4 + (l >> 4)) ^ (l & 7)) << 4);
  const char* Xp = (const char*)hX;

  // per-nf byte base addresses (frag (w*4+nf): 16 frags * 1024B = 16384B apart),
  // + lane offset; step offset is s*1024 added per load
  const ushortT* w1base = W1bf + ((size_t)e*32)*16*512;
  const ushortT* w2base = W2bf + ((size_t)e*32)*16*512;
  uint64_t sb1[4], sb2[4];
  #pragma unroll
  for (int nf = 0; nf < 4; nf++){
    sb1[nf] = (uint64_t)(uintptr_t)(w1base + (size_t)(w*4 + nf)*8192 + (l << 3));
    sb2[nf] = (uint64_t)(uintptr_t)(w2base + (size_t)(w*4 + nf)*8192 + (l << 3));
  }

  s16x8 B0[4], B1[4];
  f32x4 acc[4][4];

#define BLOAD(dst_, sb_, off_) { \
    uint64_t a_ = (sb_) + (uint64_t)(uint32_t)(off_); \
    asm volatile("global_load_dwordx4 %0, %1, off" : "=v"(dst_) : "v"(a_)); }
#define BWAIT(Bx, n_) \
  asm volatile("s_waitcnt vmcnt(" n_ ")" : "+v"(Bx[0]), "+v"(Bx[1]), "+v"(Bx[2]), "+v"(Bx[3]))
#define MFMA_STEP(Bx, A_) { \
    _Pragma("unroll") \
    for (int nf = 0; nf < 4; nf++){ \
      bf16x8 bb_ = __builtin_bit_cast(bf16x8, Bx[nf]); \
      _Pragma("unroll") \
      for (int m = 0; m < 4; m++) \
        acc[m][nf] = __builtin_amdgcn_mfma_f32_16x16x32_bf16(A_[m], bb_, acc[m][nf], 0, 0, 0); } }

#define GEMM_ASM(sbv_) { \
    { _Pragma("unroll") for (int nf = 0; nf < 4; nf++) BLOAD(B0[nf], sbv_[nf], 0u); \
      _Pragma("unroll") for (int nf = 0; nf < 4; nf++) BLOAD(B1[nf], sbv_[nf], 1024u); } \
    _Pragma("unroll") \
    for (int s = 0; s < 16; s++){ \
      bf16x8 A_[4]; \
      { const int ab_ = (s & 1) ? aB1 : aB0; \
        _Pragma("unroll") \
        for (int m = 0; m < 4; m++) A_[m] = ldfrag(Xp + ab_ + m*16384 + (s >> 1)*128); } \
      if ((s & 1) == 0){ \
        BWAIT(B0, "4"); \
        MFMA_STEP(B0, A_); \
        if (s + 2 < 16){ \
          _Pragma("unroll") for (int nf = 0; nf < 4; nf++) BLOAD(B0[nf], sbv_[nf], (uint32_t)(s + 2)*1024u); } \
      } else { \
        if (s < 15){ BWAIT(B1, "4"); } else { BWAIT(B1, "0"); } \
        MFMA_STEP(B1, A_); \
        if (s + 2 < 16){ \
          _Pragma("unroll") for (int nf = 0; nf < 4; nf++) BLOAD(B1[nf], sbv_[nf], (uint32_t)(s + 2)*1024u); } \
      } \
    } }

  // ================= GEMM1: acc = X @ W1 (barrier-free, asm-pipelined) ======
  #pragma unroll
  for (int m = 0; m < 4; m++)
    #pragma unroll
    for (int nf = 0; nf < 4; nf++) acc[m][nf] = (f32x4){0.f,0.f,0.f,0.f};
  GEMM_ASM(sb1);

  // ---- LN partial sums from fp32 acc (regs) ----
  #pragma unroll
  for (int m = 0; m < 4; m++){
    #pragma unroll
    for (int j = 0; j < 4; j++){
      float s = acc[m][0][j] + acc[m][1][j] + acc[m][2][j] + acc[m][3][j];
      float q = acc[m][0][j]*acc[m][0][j] + acc[m][1][j]*acc[m][1][j]
              + acc[m][2][j]*acc[m][2][j] + acc[m][3][j]*acc[m][3][j];
      s += __shfl_xor(s, 1); q += __shfl_xor(q, 1);
      s += __shfl_xor(s, 2); q += __shfl_xor(q, 2);
      s += __shfl_xor(s, 4); q += __shfl_xor(q, 4);
      s += __shfl_xor(s, 8); q += __shfl_xor(q, 8);
      if ((l & 15) == 0){
        int row = m*16 + (l >> 4)*4 + j;
        wsumL[w][row] = s;
        wsqL[w][row]  = q;
      }
    }
  }
  __syncthreads();   // X reads done + partials written

  if (tid < 64){
    float s = 0.f, q = 0.f;
    #pragma unroll
    for (int i = 0; i < 8; i++){ s += wsumL[i][tid]; q += wsqL[i][tid]; }
    float mu = s * (1.f/512.f);
    float var = q * (1.f/512.f) - mu*mu;
    muL[tid] = mu;
    rsL[tid] = rsqrtf(var + 1e-5f);
  }
  __syncthreads();

  // ---- LN + GELU in registers, write h (bf16) into hX (overwrite X) ----
  {
    #pragma unroll
    for (int m = 0; m < 4; m++){
      #pragma unroll
      for (int j = 0; j < 4; j++){
        int row = m*16 + (l >> 4)*4 + j;
        float mu = muL[row], rs = rsL[row];
        #pragma unroll
        for (int nf = 0; nf < 4; nf++){
          int col = w*64 + nf*16 + (l & 15);
          float g = gamma[e*512 + col];
          float b = beta [e*512 + col];
          float v = (acc[m][nf][j] - mu) * rs * g + b;
          v = gelu_f(v);
          int ss = (col >> 3) ^ (row & 7);
          *(ushortT*)((char*)hX + row*1024 + ss*16 + (col & 7)*2) = f2bfu(v);
        }
      }
    }
  }
  __syncthreads();

  // ================= GEMM2: out-tile = h @ W2 (asm-pipelined) =================
  #pragma unroll
  for (int m = 0; m < 4; m++)
    #pragma unroll
    for (int nf = 0; nf < 4; nf++) acc[m][nf] = (f32x4){0.f,0.f,0.f,0.f};
  GEMM_ASM(sb2);

  // ---- weighted store ----
  #pragma unroll
  for (int m = 0; m < 4; m++){
    #pragma unroll
    for (int j = 0; j < 4; j++){
      int row = m*16 + (l >> 4)*4 + j;
      int tok = toksL[row];
      if (tok >= 0){
        float wr = wrowL[row];
        #pragma unroll
        for (int nf = 0; nf < 4; nf++){
          int col = w*64 + nf*16 + (l & 15);
          float val = acc[m][nf][j] * wr;
          float* p = out + (size_t)tok*512 + col;
          if (SLOT == 0) *p = val; else *p += val;
        }
      }
    }
  }
#undef BLOAD
#undef BWAIT
#undef MFMA_STEP
#undef GEMM_ASM
}

extern "C" void kernel_launch(void* const* d_in, const int* in_sizes, int n_in,
                              void* d_out, int out_size, void* d_ws, size_t ws_size,
                              hipStream_t stream){
  const float* x     = (const float*)d_in[0];
  const float* Wg    = (const float*)d_in[1];
  const float* W1    = (const float*)d_in[2];
  const float* gamma = (const float*)d_in[3];
  const float* beta  = (const float*)d_in[4];
  const float* W2    = (const float*)d_in[5];
  float* out = (float*)d_out;

  char* ws = (char*)d_ws;
  size_t off = 0;
  ushortT* xbf   = (ushortT*)(ws + off); off += (size_t)NTOK*512*2;      // 128 MB
  ushortT* W1bf  = (ushortT*)(ws + off); off += (size_t)8*512*512*2;     // 4 MB
  ushortT* W2bf  = (ushortT*)(ws + off); off += (size_t)8*512*512*2;     // 4 MB
  int*     lists = (int*)(ws + off);     off += (size_t)16*NTOK*4;       // 8 MB
  float*   wtp   = (float*)(ws + off);   off += (size_t)2*NTOK*4;        // 1 MB
  int*     epair = (int*)(ws + off);     off += (size_t)NTOK*4;          // 0.5 MB
  int*     cursors = (int*)(ws + off);   off += 256;

  zero_cursors_kernel<<<1, 64, 0, stream>>>(cursors);
  prep_w_kernel<<<1024, 256, 0, stream>>>(W1, W2, W1bf, W2bf);
  gating_kernel<<<NTOK/64, 256, 0, stream>>>(x, Wg, xbf, epair, wtp);
  scatter_kernel<<<NTOK/256, 256, 0, stream>>>(epair, cursors, lists);
  expert_kernel<0><<<2056, 512, 0, stream>>>(xbf, W1bf, W2bf, gamma, beta, wtp, cursors, lists, out);
  expert_kernel<1><<<2056, 512, 0, stream>>>(xbf, W1bf, W2bf, gamma, beta, wtp, cursors, lists, out);
}